// Round 7
// baseline (158.556 us; speedup 1.0000x reference)
//
#include <hip/hip_runtime.h>
#include <math.h>

// MoE top-2-of-8: B=1024, I=512, H=2048, O=512, E=8, K=2.
// R7: barrier-free K-loop. W n-panel (32 cols x 512 k) staged fp32->bf16 [n][k]
// into LDS exactly once; A fragments (16x16x32 layout A[m=l15][k=q*8+j]) are
// per-lane DIRECT global b128 loads (xb/hb, L2-hot, 1 KB/instr fully used).
// Steady state: 2 global A + 2 LDS B reads -> 4 MFMAs, no barriers, no ds_write.
// 512 blocks x 8 waves both GEMMs (2 blocks/CU, 16 waves/CU), wave = 32-row
// m-strip, acc[2][2]. fc2 split-K=4 -> y4 f32 partials, deterministic combine.

#define B_TOK 1024
#define I_DIM 512
#define H_DIM 2048
#define O_DIM 512
#define E_NUM 8

#define WS_COUNTS   0                    // 8 ints (written by scatter)
#define WS_OFFSETS  32                   // 8 ints
#define WS_TOK_E    64                   // [1024][2] int
#define WS_TOK_W    8256                 // [1024][2] float
#define WS_SLOT_TOK 16448                // [2048] int
#define WS_SLOT_WT  24640                // [2048] float
#define WS_TOK_SLOT 32832                // [1024][2] int
#define WS_XB       65536                // [1024][512] bf16 = 1 MB
#define WS_HB       (WS_XB + 1048576)    // [2048][2048] bf16 = 8 MB
#define WS_Y4       (WS_HB + 8388608)    // [4][2048][512] f32 = 16 MB

typedef __attribute__((ext_vector_type(8))) __bf16 bf16x8;
typedef __attribute__((ext_vector_type(4))) __bf16 bf16x4;
typedef __attribute__((ext_vector_type(4))) float f32x4;

#define MFMA16 __builtin_amdgcn_mfma_f32_16x16x32_bf16

// ---------------------------------------------------------------------------
// Gating: one wave per token. Also converts the token's x row to bf16 (xb).
__global__ __launch_bounds__(256) void gating_kernel(
    const float* __restrict__ x, const float* __restrict__ Wg,
    const float* __restrict__ bg, __bf16* __restrict__ xb,
    int* __restrict__ tok_e, float* __restrict__ tok_w)
{
    const int lane = threadIdx.x & 63;
    const int t = blockIdx.x * 4 + (threadIdx.x >> 6);
    const float4* x4 = (const float4*)(x + (size_t)t * I_DIM);
    float4 va = x4[lane], vb = x4[lane + 64];
    bf16x4 oa, ob;
    oa[0] = (__bf16)va.x; oa[1] = (__bf16)va.y;
    oa[2] = (__bf16)va.z; oa[3] = (__bf16)va.w;
    ob[0] = (__bf16)vb.x; ob[1] = (__bf16)vb.y;
    ob[2] = (__bf16)vb.z; ob[3] = (__bf16)vb.w;
    *(bf16x4*)(xb + (size_t)t * I_DIM + lane * 4) = oa;
    *(bf16x4*)(xb + (size_t)t * I_DIM + 256 + lane * 4) = ob;

    float acc[8];
#pragma unroll
    for (int e = 0; e < 8; ++e) acc[e] = 0.f;
    float xv[8] = {va.x, va.y, va.z, va.w, vb.x, vb.y, vb.z, vb.w};
#pragma unroll
    for (int u = 0; u < 8; ++u) {
        int i = (u < 4) ? (lane * 4 + u) : (256 + lane * 4 + u - 4);
        const float4* wr = (const float4*)(Wg + (size_t)i * 8);
        float4 wa = wr[0], wb2 = wr[1];
        acc[0] = fmaf(xv[u], wa.x, acc[0]);
        acc[1] = fmaf(xv[u], wa.y, acc[1]);
        acc[2] = fmaf(xv[u], wa.z, acc[2]);
        acc[3] = fmaf(xv[u], wa.w, acc[3]);
        acc[4] = fmaf(xv[u], wb2.x, acc[4]);
        acc[5] = fmaf(xv[u], wb2.y, acc[5]);
        acc[6] = fmaf(xv[u], wb2.z, acc[6]);
        acc[7] = fmaf(xv[u], wb2.w, acc[7]);
    }
#pragma unroll
    for (int off = 32; off > 0; off >>= 1)
#pragma unroll
        for (int e = 0; e < 8; ++e)
            acc[e] += __shfl_xor(acc[e], off, 64);
    if (lane == 0) {
        float l[8];
#pragma unroll
        for (int e = 0; e < 8; ++e) l[e] = acc[e] + bg[e];
        int e0 = 0;
        for (int e = 1; e < 8; ++e) if (l[e] > l[e0]) e0 = e;
        int e1 = (e0 == 0) ? 1 : 0;
        for (int e = 0; e < 8; ++e) {
            if (e == e0) continue;
            if (l[e] > l[e1]) e1 = e;
        }
        float w0 = 1.f / (1.f + expf(l[e1] - l[e0]));  // p0/(p0+p1)
        tok_e[t * 2]     = e0;
        tok_e[t * 2 + 1] = e1;
        tok_w[t * 2]     = w0;
        tok_w[t * 2 + 1] = 1.f - w0;
    }
}

// Single block: histogram -> prefix -> scatter into per-expert slot lists.
__global__ __launch_bounds__(1024) void scatter_kernel(
    const int* __restrict__ tok_e, const float* __restrict__ tok_w,
    int* __restrict__ counts, int* __restrict__ offsets,
    int* __restrict__ slot_token, float* __restrict__ slot_wt,
    int* __restrict__ tok_slot)
{
    __shared__ int hist[8], soff[8], scur[8];
    const int tid = threadIdx.x;
    if (tid < 8) { hist[tid] = 0; scur[tid] = 0; }
    __syncthreads();
    const int e0 = tok_e[tid * 2], e1 = tok_e[tid * 2 + 1];
    atomicAdd(&hist[e0], 1);
    atomicAdd(&hist[e1], 1);
    __syncthreads();
    if (tid == 0) {
        int run = 0;
        for (int e = 0; e < 8; ++e) { soff[e] = run; run += hist[e]; }
    }
    __syncthreads();
    if (tid < 8) { counts[tid] = hist[tid]; offsets[tid] = soff[tid]; }
#pragma unroll
    for (int k = 0; k < 2; ++k) {
        int e = tok_e[tid * 2 + k];
        int pos = atomicAdd(&scur[e], 1);
        int slot = soff[e] + pos;
        slot_token[slot] = tid;
        slot_wt[slot] = tok_w[tid * 2 + k];
        tok_slot[tid * 2 + k] = slot;
    }
}

// ---------------------------------------------------------------------------
// Barrier-free weight-stationary GEMM. 512 threads = 8 waves; BN=32 n-panel in
// LDS (staged once); each wave owns a 32-row m-strip, acc[2][2], K-chunk 512.
// IS_FC1:  A=xb rows gathered via slot_token; Out=hb bf16 (+bias, relu)
// !IS_FC1: A=hb rows direct, k-chunk kc; Out=y4[kc] f32 partials (bias deferred)
template <bool IS_FC1>
__global__ __launch_bounds__(512) void moe_gemm(
    const __bf16* __restrict__ A, const float* __restrict__ Wf,
    const float* __restrict__ bias,
    const int* __restrict__ counts, const int* __restrict__ offsets,
    const int* __restrict__ slot_token,
    __bf16* __restrict__ hb, float* __restrict__ y4)
{
    constexpr int NW   = IS_FC1 ? H_DIM : O_DIM;   // W col count
    constexpr int KW   = IS_FC1 ? I_DIM : H_DIM;   // W row count
    constexpr int ASTR = IS_FC1 ? I_DIM : H_DIM;   // A row stride

    const int e  = blockIdx.z;
    const int kc = IS_FC1 ? 0 : (int)blockIdx.y;
    const int k0 = kc * 512;
    const int n0 = blockIdx.x * 32;
    const int Me = counts[e];
    if (Me == 0) return;
    const int off = offsets[e];
    const float* W = Wf + (size_t)e * KW * NW;

    // [n][k] bf16, row stride 520 (1040 B: +16 B pad -> bank-spread b128 reads)
    __shared__ __align__(16) __bf16 Bs[32 * 520];

    const int tid = threadIdx.x;
    // ---- stage W panel: rows k0..k0+512, cols n0..n0+32, fp32 -> bf16 ----
    {
        const int bn = tid & 31;          // col
        const int kg = tid >> 5;          // k-group (16 groups x 32 k)
        const float* wp = W + (size_t)(k0 + kg * 32) * NW + n0 + bn;
#pragma unroll
        for (int j4 = 0; j4 < 8; ++j4) {
            float v0 = wp[(size_t)(j4 * 4 + 0) * NW];
            float v1 = wp[(size_t)(j4 * 4 + 1) * NW];
            float v2 = wp[(size_t)(j4 * 4 + 2) * NW];
            float v3 = wp[(size_t)(j4 * 4 + 3) * NW];
            bf16x4 o;
            o[0] = (__bf16)v0; o[1] = (__bf16)v1;
            o[2] = (__bf16)v2; o[3] = (__bf16)v3;
            *(bf16x4*)&Bs[bn * 520 + kg * 32 + j4 * 4] = o;
        }
    }
    __syncthreads();                      // the ONLY block-wide barrier

    const int lane = tid & 63, w = tid >> 6;       // 8 waves
    const int l15 = lane & 15, q = lane >> 4;

    for (int m0 = w * 32; m0 < Me; m0 += 256) {
        int mA = m0 + l15;      if (mA >= Me) mA = Me - 1;
        int mB = m0 + 16 + l15; if (mB >= Me) mB = Me - 1;
        const __bf16 *a0, *a1;
        if (IS_FC1) {
            a0 = A + (size_t)slot_token[off + mA] * ASTR + q * 8;
            a1 = A + (size_t)slot_token[off + mB] * ASTR + q * 8;
        } else {
            a0 = A + (size_t)(off + mA) * ASTR + k0 + q * 8;
            a1 = A + (size_t)(off + mB) * ASTR + k0 + q * 8;
        }

        f32x4 acc[2][2] = {};
#pragma unroll 4
        for (int ks = 0; ks < 16; ++ks) {
            bf16x8 af0 = *(const bf16x8*)(a0 + ks * 32);
            bf16x8 af1 = *(const bf16x8*)(a1 + ks * 32);
            bf16x8 bf0 = *(const bf16x8*)&Bs[l15 * 520 + ks * 32 + q * 8];
            bf16x8 bf1 = *(const bf16x8*)&Bs[(16 + l15) * 520 + ks * 32 + q * 8];
            acc[0][0] = MFMA16(af0, bf0, acc[0][0], 0, 0, 0);
            acc[0][1] = MFMA16(af0, bf1, acc[0][1], 0, 0, 0);
            acc[1][0] = MFMA16(af1, bf0, acc[1][0], 0, 0, 0);
            acc[1][1] = MFMA16(af1, bf1, acc[1][1], 0, 0, 0);
        }

        // epilogue: C/D layout col=l15, row=q*4+reg (verified m89)
#pragma unroll
        for (int jj = 0; jj < 2; ++jj) {
            const int gn = n0 + jj * 16 + l15;
            if (IS_FC1) {
                const float bv = bias[e * H_DIM + gn];
#pragma unroll
                for (int i = 0; i < 2; ++i)
#pragma unroll
                    for (int r = 0; r < 4; ++r) {
                        int m = m0 + i * 16 + q * 4 + r;
                        if (m < Me) {
                            float v = acc[i][jj][r] + bv;
                            hb[(size_t)(off + m) * H_DIM + gn] =
                                (__bf16)fmaxf(v, 0.f);
                        }
                    }
            } else {
#pragma unroll
                for (int i = 0; i < 2; ++i)
#pragma unroll
                    for (int r = 0; r < 4; ++r) {
                        int m = m0 + i * 16 + q * 4 + r;
                        if (m < Me)
                            y4[((size_t)kc * 2048 + off + m) * O_DIM + gn] =
                                acc[i][jj][r];
                    }
            }
        }
    }
}

// out[t][c] = sum_k w_k * (b2[e_k][c] + sum_kc y4[kc][slot_k][c])
__global__ __launch_bounds__(256) void combine_kernel(
    const float* __restrict__ y4, const float* __restrict__ b2,
    const int* __restrict__ tok_slot, const int* __restrict__ tok_e,
    const float* __restrict__ tok_w, float* __restrict__ out)
{
    const int idx = blockIdx.x * 256 + threadIdx.x;   // B*O/4
    const int t = idx >> 7;
    const int c = (idx & 127) * 4;
    float4 sum = {0.f, 0.f, 0.f, 0.f};
#pragma unroll
    for (int k = 0; k < 2; ++k) {
        const int s = tok_slot[t * 2 + k];
        const int e = tok_e[t * 2 + k];
        const float wgt = tok_w[t * 2 + k];
        float4 a = *(const float4*)(b2 + (size_t)e * O_DIM + c);
#pragma unroll
        for (int kc = 0; kc < 4; ++kc) {
            float4 v = *(const float4*)(y4 + ((size_t)kc * 2048 + s) * O_DIM + c);
            a.x += v.x; a.y += v.y; a.z += v.z; a.w += v.w;
        }
        sum.x += wgt * a.x; sum.y += wgt * a.y;
        sum.z += wgt * a.z; sum.w += wgt * a.w;
    }
    *(float4*)(out + (size_t)t * O_DIM + c) = sum;
}

extern "C" void kernel_launch(void* const* d_in, const int* in_sizes, int n_in,
                              void* d_out, int out_size, void* d_ws, size_t ws_size,
                              hipStream_t stream)
{
    const float* x  = (const float*)d_in[0];
    const float* Wg = (const float*)d_in[1];
    const float* bg = (const float*)d_in[2];
    const float* W1 = (const float*)d_in[3];
    const float* b1 = (const float*)d_in[4];
    const float* W2 = (const float*)d_in[5];
    const float* b2 = (const float*)d_in[6];
    float* out = (float*)d_out;
    char* ws = (char*)d_ws;

    int*    counts   = (int*)(ws + WS_COUNTS);
    int*    offsets  = (int*)(ws + WS_OFFSETS);
    int*    tok_e    = (int*)(ws + WS_TOK_E);
    float*  tok_w    = (float*)(ws + WS_TOK_W);
    int*    slot_tok = (int*)(ws + WS_SLOT_TOK);
    float*  slot_wt  = (float*)(ws + WS_SLOT_WT);
    int*    tok_slot = (int*)(ws + WS_TOK_SLOT);
    __bf16* xb       = (__bf16*)(ws + WS_XB);
    __bf16* hb       = (__bf16*)(ws + WS_HB);
    float*  y4       = (float*)(ws + WS_Y4);

    gating_kernel<<<B_TOK / 4, 256, 0, stream>>>(x, Wg, bg, xb, tok_e, tok_w);
    scatter_kernel<<<1, B_TOK, 0, stream>>>(tok_e, tok_w, counts, offsets,
                                            slot_tok, slot_wt, tok_slot);
    // fc1: 64 n-panels x 8 experts = 512 blocks (2/CU, 16 waves/CU)
    moe_gemm<true><<<dim3(64, 1, 8), 512, 0, stream>>>(
        xb, W1, b1, counts, offsets, slot_tok, hb, y4);
    // fc2: 16 n-panels x 4 k-chunks x 8 experts = 512 blocks
    moe_gemm<false><<<dim3(16, 4, 8), 512, 0, stream>>>(
        hb, W2, b2, counts, offsets, slot_tok, hb, y4);
    combine_kernel<<<(B_TOK * O_DIM / 4) / 256, 256, 0, stream>>>(
        y4, b2, tok_slot, tok_e, tok_w, out);
}

// Round 8
// 156.349 us; speedup vs baseline: 1.0141x; 1.0141x over previous
//
#include <hip/hip_runtime.h>
#include <math.h>

// MoE top-2-of-8: B=1024, I=512, H=2048, O=512, E=8, K=2.
// R8: contiguous W streaming. Each block owns a BN=64 x K=512 W-panel; W is
// read with CONTIGUOUS 256B row-segments (float4/lane) and transposed into
// LDS [n][k] bf16 via k-pair-packed ds_write_b32 (replaces R6/R7's strided
// 128B-column global reads -- the common ~20us/GEMM cost). Panel staged in two
// 256-k chunks, chunk 1 overlapped with chunk-0 compute. A-frags stay direct
// per-lane global b128 (R7 pattern). fc1: 32n x 8e = 256 blocks, full-K,
// bf16+relu epilogue. fc2: 8n x 4kc x 8e = 256 blocks -> y4 f32 partials,
// deterministic combine (no atomics).

#define B_TOK 1024
#define I_DIM 512
#define H_DIM 2048
#define O_DIM 512
#define E_NUM 8

#define WS_COUNTS   0                    // 8 ints (written by scatter)
#define WS_OFFSETS  32                   // 8 ints
#define WS_TOK_E    64                   // [1024][2] int
#define WS_TOK_W    8256                 // [1024][2] float
#define WS_SLOT_TOK 16448                // [2048] int
#define WS_SLOT_WT  24640                // [2048] float
#define WS_TOK_SLOT 32832                // [1024][2] int
#define WS_XB       65536                // [1024][512] bf16 = 1 MB
#define WS_HB       (WS_XB + 1048576)    // [2048][2048] bf16 = 8 MB
#define WS_Y4       (WS_HB + 8388608)    // [4][2048][512] f32 = 16 MB

typedef __attribute__((ext_vector_type(8))) __bf16 bf16x8;
typedef __attribute__((ext_vector_type(4))) __bf16 bf16x4;
typedef __attribute__((ext_vector_type(2))) __bf16 bf16x2;
typedef __attribute__((ext_vector_type(4))) float f32x4;

#define MFMA16 __builtin_amdgcn_mfma_f32_16x16x32_bf16
#define BSTR 520   // Bs row stride (elems): +8 pad, proven conflict-free reads (R7)

// ---------------------------------------------------------------------------
// Gating: one wave per token. Also converts the token's x row to bf16 (xb).
__global__ __launch_bounds__(256) void gating_kernel(
    const float* __restrict__ x, const float* __restrict__ Wg,
    const float* __restrict__ bg, __bf16* __restrict__ xb,
    int* __restrict__ tok_e, float* __restrict__ tok_w)
{
    const int lane = threadIdx.x & 63;
    const int t = blockIdx.x * 4 + (threadIdx.x >> 6);
    const float4* x4 = (const float4*)(x + (size_t)t * I_DIM);
    float4 va = x4[lane], vb = x4[lane + 64];
    bf16x4 oa, ob;
    oa[0] = (__bf16)va.x; oa[1] = (__bf16)va.y;
    oa[2] = (__bf16)va.z; oa[3] = (__bf16)va.w;
    ob[0] = (__bf16)vb.x; ob[1] = (__bf16)vb.y;
    ob[2] = (__bf16)vb.z; ob[3] = (__bf16)vb.w;
    *(bf16x4*)(xb + (size_t)t * I_DIM + lane * 4) = oa;
    *(bf16x4*)(xb + (size_t)t * I_DIM + 256 + lane * 4) = ob;

    float acc[8];
#pragma unroll
    for (int e = 0; e < 8; ++e) acc[e] = 0.f;
    float xv[8] = {va.x, va.y, va.z, va.w, vb.x, vb.y, vb.z, vb.w};
#pragma unroll
    for (int u = 0; u < 8; ++u) {
        int i = (u < 4) ? (lane * 4 + u) : (256 + lane * 4 + u - 4);
        const float4* wr = (const float4*)(Wg + (size_t)i * 8);
        float4 wa = wr[0], wb2 = wr[1];
        acc[0] = fmaf(xv[u], wa.x, acc[0]);
        acc[1] = fmaf(xv[u], wa.y, acc[1]);
        acc[2] = fmaf(xv[u], wa.z, acc[2]);
        acc[3] = fmaf(xv[u], wa.w, acc[3]);
        acc[4] = fmaf(xv[u], wb2.x, acc[4]);
        acc[5] = fmaf(xv[u], wb2.y, acc[5]);
        acc[6] = fmaf(xv[u], wb2.z, acc[6]);
        acc[7] = fmaf(xv[u], wb2.w, acc[7]);
    }
#pragma unroll
    for (int off = 32; off > 0; off >>= 1)
#pragma unroll
        for (int e = 0; e < 8; ++e)
            acc[e] += __shfl_xor(acc[e], off, 64);
    if (lane == 0) {
        float l[8];
#pragma unroll
        for (int e = 0; e < 8; ++e) l[e] = acc[e] + bg[e];
        int e0 = 0;
        for (int e = 1; e < 8; ++e) if (l[e] > l[e0]) e0 = e;
        int e1 = (e0 == 0) ? 1 : 0;
        for (int e = 0; e < 8; ++e) {
            if (e == e0) continue;
            if (l[e] > l[e1]) e1 = e;
        }
        float w0 = 1.f / (1.f + expf(l[e1] - l[e0]));  // p0/(p0+p1)
        tok_e[t * 2]     = e0;
        tok_e[t * 2 + 1] = e1;
        tok_w[t * 2]     = w0;
        tok_w[t * 2 + 1] = 1.f - w0;
    }
}

// Single block: histogram -> prefix -> scatter into per-expert slot lists.
__global__ __launch_bounds__(1024) void scatter_kernel(
    const int* __restrict__ tok_e, const float* __restrict__ tok_w,
    int* __restrict__ counts, int* __restrict__ offsets,
    int* __restrict__ slot_token, float* __restrict__ slot_wt,
    int* __restrict__ tok_slot)
{
    __shared__ int hist[8], soff[8], scur[8];
    const int tid = threadIdx.x;
    if (tid < 8) { hist[tid] = 0; scur[tid] = 0; }
    __syncthreads();
    const int e0 = tok_e[tid * 2], e1 = tok_e[tid * 2 + 1];
    atomicAdd(&hist[e0], 1);
    atomicAdd(&hist[e1], 1);
    __syncthreads();
    if (tid == 0) {
        int run = 0;
        for (int e = 0; e < 8; ++e) { soff[e] = run; run += hist[e]; }
    }
    __syncthreads();
    if (tid < 8) { counts[tid] = hist[tid]; offsets[tid] = soff[tid]; }
#pragma unroll
    for (int k = 0; k < 2; ++k) {
        int e = tok_e[tid * 2 + k];
        int pos = atomicAdd(&scur[e], 1);
        int slot = soff[e] + pos;
        slot_token[slot] = tid;
        slot_wt[slot] = tok_w[tid * 2 + k];
        tok_slot[tid * 2 + k] = slot;
    }
}

// ---------------------------------------------------------------------------
// Weight-stationary GEMM, contiguous-W staging. 512 thr = 8 waves, BN=64,
// K-span 512 (2 staged chunks of 256). Wave = 32-row m-strip, acc[2][4].
// IS_FC1:  A=xb gathered via slot_token, W=W1[e] (N=2048), Out=hb (+bias,relu)
// !IS_FC1: A=hb direct (k-chunk kc), W=W2[e] (N=512), Out=y4[kc] f32 partials
template <bool IS_FC1>
__global__ __launch_bounds__(512) void moe_gemm(
    const __bf16* __restrict__ A, const float* __restrict__ Wf,
    const float* __restrict__ bias,
    const int* __restrict__ counts, const int* __restrict__ offsets,
    const int* __restrict__ slot_token,
    __bf16* __restrict__ hb, float* __restrict__ y4)
{
    constexpr int NW   = IS_FC1 ? H_DIM : O_DIM;   // W col count (row stride)
    constexpr int ASTR = IS_FC1 ? I_DIM : H_DIM;   // A row stride

    const int e  = blockIdx.z;
    const int kc = IS_FC1 ? 0 : (int)blockIdx.y;
    const int k0 = kc * 512;
    const int n0 = blockIdx.x * 64;
    const int Me = counts[e];
    if (Me == 0) return;
    const int off = offsets[e];
    const float* W = Wf + (size_t)e * (IS_FC1 ? I_DIM * H_DIM : H_DIM * O_DIM);

    __shared__ __align__(16) __bf16 Bs[64 * BSTR];   // [n][k-local], 66.5 KB

    const int tid = threadIdx.x;
    const int lane = tid & 63, w = tid >> 6;
    const int l15 = lane & 15, q = lane >> 4;

    // ---- contiguous staging of one 256-k chunk, transposed into Bs ----
    // thread unit u: k-row-pair p (0..127), col-quad c4 (0..15).
    // global: two contiguous float4 at rows (2p, 2p+1); LDS: 4 packed b32.
    auto stage_chunk = [&](int ch) {
        const int kb = k0 + ch * 256;
#pragma unroll
        for (int i = 0; i < 4; ++i) {
            const int u = tid + 512 * i;
            const int p = u >> 4, c4 = u & 15;
            const float* wp = W + (size_t)(kb + 2 * p) * NW + n0 + c4 * 4;
            float4 r0 = *(const float4*)wp;
            float4 r1 = *(const float4*)(wp + NW);
            const float* f0 = (const float*)&r0;
            const float* f1 = (const float*)&r1;
#pragma unroll
            for (int j = 0; j < 4; ++j) {
                bf16x2 pk;
                pk[0] = (__bf16)f0[j];
                pk[1] = (__bf16)f1[j];
                *(bf16x2*)&Bs[(size_t)(c4 * 4 + j) * BSTR + ch * 256 + 2 * p] = pk;
            }
        }
    };

    // ---- per-m-tile compute over ks range [ks0, ks1) ----
    auto set_aptr = [&](int m0, const __bf16*& a0, const __bf16*& a1) {
        int mA = m0 + l15;      if (mA >= Me) mA = Me - 1;
        int mB = m0 + 16 + l15; if (mB >= Me) mB = Me - 1;
        if (IS_FC1) {
            a0 = A + (size_t)slot_token[off + mA] * ASTR + q * 8;
            a1 = A + (size_t)slot_token[off + mB] * ASTR + q * 8;
        } else {
            a0 = A + (size_t)(off + mA) * ASTR + k0 + q * 8;
            a1 = A + (size_t)(off + mB) * ASTR + k0 + q * 8;
        }
    };
    auto compute = [&](const __bf16* a0, const __bf16* a1,
                       f32x4 (&acc)[2][4], int ks0, int ks1) {
#pragma unroll 4
        for (int ks = ks0; ks < ks1; ++ks) {
            bf16x8 af0 = *(const bf16x8*)(a0 + ks * 32);
            bf16x8 af1 = *(const bf16x8*)(a1 + ks * 32);
#pragma unroll
            for (int jj = 0; jj < 4; ++jj) {
                bf16x8 bf = *(const bf16x8*)
                    &Bs[(size_t)(jj * 16 + l15) * BSTR + ks * 32 + q * 8];
                acc[0][jj] = MFMA16(af0, bf, acc[0][jj], 0, 0, 0);
                acc[1][jj] = MFMA16(af1, bf, acc[1][jj], 0, 0, 0);
            }
        }
    };
    // epilogue: C/D layout col=l15, row=q*4+reg (verified m89)
    auto epilogue = [&](int m0, f32x4 (&acc)[2][4]) {
#pragma unroll
        for (int jj = 0; jj < 4; ++jj) {
            const int gn = n0 + jj * 16 + l15;
            if (IS_FC1) {
                const float bv = bias[e * H_DIM + gn];
#pragma unroll
                for (int i = 0; i < 2; ++i)
#pragma unroll
                    for (int r = 0; r < 4; ++r) {
                        int m = m0 + i * 16 + q * 4 + r;
                        if (m < Me) {
                            float v = acc[i][jj][r] + bv;
                            hb[(size_t)(off + m) * H_DIM + gn] =
                                (__bf16)fmaxf(v, 0.f);
                        }
                    }
            } else {
#pragma unroll
                for (int i = 0; i < 2; ++i)
#pragma unroll
                    for (int r = 0; r < 4; ++r) {
                        int m = m0 + i * 16 + q * 4 + r;
                        if (m < Me)
                            y4[((size_t)kc * 2048 + off + m) * O_DIM + gn] =
                                acc[i][jj][r];
                    }
            }
        }
    };

    stage_chunk(0);
    __syncthreads();                       // chunk 0 resident
    stage_chunk(1);                        // issue chunk 1 (disjoint LDS region)

    const bool act0 = (w * 32 < Me);
    int m0 = w * 32;
    f32x4 acc[2][4] = {};
    const __bf16 *a0 = nullptr, *a1 = nullptr;
    if (act0) {
        set_aptr(m0, a0, a1);
        compute(a0, a1, acc, 0, 8);        // chunk-0 compute overlaps chunk-1 stage
    }
    __syncthreads();                       // chunk 1 resident (uniform barrier)
    if (act0) {
        compute(a0, a1, acc, 8, 16);
        epilogue(m0, acc);
    }
    for (m0 = w * 32 + 256; m0 < Me; m0 += 256) {   // rare overflow tiles
        f32x4 acc2[2][4] = {};
        set_aptr(m0, a0, a1);
        compute(a0, a1, acc2, 0, 16);
        epilogue(m0, acc2);
    }
}

// out[t][c] = sum_k w_k * (b2[e_k][c] + sum_kc y4[kc][slot_k][c])
__global__ __launch_bounds__(256) void combine_kernel(
    const float* __restrict__ y4, const float* __restrict__ b2,
    const int* __restrict__ tok_slot, const int* __restrict__ tok_e,
    const float* __restrict__ tok_w, float* __restrict__ out)
{
    const int idx = blockIdx.x * 256 + threadIdx.x;   // B*O/4
    const int t = idx >> 7;
    const int c = (idx & 127) * 4;
    float4 sum = {0.f, 0.f, 0.f, 0.f};
#pragma unroll
    for (int k = 0; k < 2; ++k) {
        const int s = tok_slot[t * 2 + k];
        const int e = tok_e[t * 2 + k];
        const float wgt = tok_w[t * 2 + k];
        float4 a = *(const float4*)(b2 + (size_t)e * O_DIM + c);
#pragma unroll
        for (int kc = 0; kc < 4; ++kc) {
            float4 v = *(const float4*)(y4 + ((size_t)kc * 2048 + s) * O_DIM + c);
            a.x += v.x; a.y += v.y; a.z += v.z; a.w += v.w;
        }
        sum.x += wgt * a.x; sum.y += wgt * a.y;
        sum.z += wgt * a.z; sum.w += wgt * a.w;
    }
    *(float4*)(out + (size_t)t * O_DIM + c) = sum;
}

extern "C" void kernel_launch(void* const* d_in, const int* in_sizes, int n_in,
                              void* d_out, int out_size, void* d_ws, size_t ws_size,
                              hipStream_t stream)
{
    const float* x  = (const float*)d_in[0];
    const float* Wg = (const float*)d_in[1];
    const float* bg = (const float*)d_in[2];
    const float* W1 = (const float*)d_in[3];
    const float* b1 = (const float*)d_in[4];
    const float* W2 = (const float*)d_in[5];
    const float* b2 = (const float*)d_in[6];
    float* out = (float*)d_out;
    char* ws = (char*)d_ws;

    int*    counts   = (int*)(ws + WS_COUNTS);
    int*    offsets  = (int*)(ws + WS_OFFSETS);
    int*    tok_e    = (int*)(ws + WS_TOK_E);
    float*  tok_w    = (float*)(ws + WS_TOK_W);
    int*    slot_tok = (int*)(ws + WS_SLOT_TOK);
    float*  slot_wt  = (float*)(ws + WS_SLOT_WT);
    int*    tok_slot = (int*)(ws + WS_TOK_SLOT);
    __bf16* xb       = (__bf16*)(ws + WS_XB);
    __bf16* hb       = (__bf16*)(ws + WS_HB);
    float*  y4       = (float*)(ws + WS_Y4);

    gating_kernel<<<B_TOK / 4, 256, 0, stream>>>(x, Wg, bg, xb, tok_e, tok_w);
    scatter_kernel<<<1, B_TOK, 0, stream>>>(tok_e, tok_w, counts, offsets,
                                            slot_tok, slot_wt, tok_slot);
    // fc1: 32 n-panels x 8 experts = 256 blocks (1/CU, whole chip)
    moe_gemm<true><<<dim3(32, 1, 8), 512, 0, stream>>>(
        xb, W1, b1, counts, offsets, slot_tok, hb, y4);
    // fc2: 8 n-panels x 4 k-chunks x 8 experts = 256 blocks
    moe_gemm<false><<<dim3(8, 4, 8), 512, 0, stream>>>(
        hb, W2, b2, counts, offsets, slot_tok, hb, y4);
    combine_kernel<<<(B_TOK * O_DIM / 4) / 256, 256, 0, stream>>>(
        y4, b2, tok_slot, tok_e, tok_w, out);
}